// Round 2
// baseline (18051.891 us; speedup 1.0000x reference)
//
#include <hip/hip_runtime.h>
#include <stdint.h>

#define E    512
#define H    8
#define DH   64
#define BB   8
#define SS   24
#define FF   2048
#define NL   3
#define VTOK 32000
#define LBUF 25
#define ML   24
#define START_ID 1

// ===========================================================================
// Encoder-side kernels (host-sequenced; ~40 dispatches total, real work each)
// ===========================================================================

__global__ void enc_embed_kernel(const int* __restrict__ inp, const float* __restrict__ emb,
                                 float* __restrict__ x) {
  int r = blockIdx.x;
  int s = r / BB, b = r % BB;
  int tok = inp[b * SS + s];
  const float* er = emb + (size_t)tok * E;
  for (int e = threadIdx.x; e < E; e += blockDim.x) {
    int j = e >> 1;
    double dv = exp(-((double)(2 * j)) * (log(10000.0) / (double)E));
    double ang = (double)s * dv;
    double pe = (e & 1) ? cos(ang) : sin(ang);
    x[(size_t)r * E + e] = er[e] + (float)pe;
  }
}

__global__ __launch_bounds__(256) void ln_kernel(const float* __restrict__ x,
                          const float* __restrict__ g,
                          const float* __restrict__ bta, float* __restrict__ y) {
  int r = blockIdx.x;
  int t = threadIdx.x;
  const float* xr = x + (size_t)r * E;
  float a0 = xr[t], a1 = xr[t + 256];
  __shared__ float red[256];
  red[t] = a0 + a1;
  __syncthreads();
  for (int s = 128; s > 0; s >>= 1) { if (t < s) red[t] += red[t + s]; __syncthreads(); }
  float m = red[0] * (1.0f / (float)E);
  __syncthreads();
  float d0 = a0 - m, d1 = a1 - m;
  red[t] = d0 * d0 + d1 * d1;
  __syncthreads();
  for (int s = 128; s > 0; s >>= 1) { if (t < s) red[t] += red[t + s]; __syncthreads(); }
  float v = red[0] * (1.0f / (float)E);
  float rstd = 1.0f / sqrtf(v + 1e-5f);
  y[(size_t)r * E + t]       = d0 * rstd * g[t]       + bta[t];
  y[(size_t)r * E + t + 256] = d1 * rstd * g[t + 256] + bta[t + 256];
}

// C[M,N] = A[M,K] @ W[K,N(ldw)] (+bias,resid,relu / or k-split partials)
__global__ __launch_bounds__(256) void fgemm_kernel(
    const float* __restrict__ A, int K,
    const float* __restrict__ W, int ldw, int N,
    const float* __restrict__ bias,
    const float* __restrict__ resid,
    float* __restrict__ C, int relu) {
  __shared__ float Al[8 * 512];
  __shared__ float red[16 * 512];
  int t = threadIdx.x;
  int c0 = blockIdx.x * 64;
  int s = blockIdx.y;
  int row0 = blockIdx.z * 8;
  int kbase = s * 512;
  for (int i = t; i < 1024; i += 256) {
    int r = i >> 7, cc = i & 127;
    ((float4*)Al)[i] = *(const float4*)(A + (size_t)(row0 + r) * K + kbase + (cc << 2));
  }
  __syncthreads();
  int tc = t & 15, tk = t >> 4;
  int col = c0 + (tc << 2);
  float acc[8][4];
#pragma unroll
  for (int m = 0; m < 8; ++m) { acc[m][0] = acc[m][1] = acc[m][2] = acc[m][3] = 0.f; }
  const float4* wp = (const float4*)(W + (size_t)kbase * ldw + col);
  const size_t ld4 = (size_t)(ldw >> 2);
#pragma unroll 8
  for (int i = 0; i < 32; ++i) {
    int k = tk + (i << 4);
    float4 wv = wp[(size_t)k * ld4];
#pragma unroll
    for (int m = 0; m < 8; ++m) {
      float a = Al[m * 512 + k];
      acc[m][0] += a * wv.x; acc[m][1] += a * wv.y;
      acc[m][2] += a * wv.z; acc[m][3] += a * wv.w;
    }
  }
#pragma unroll
  for (int m = 0; m < 8; ++m) {
    float4* rr = (float4*)&red[tk * 512 + m * 64 + (tc << 2)];
    *rr = make_float4(acc[m][0], acc[m][1], acc[m][2], acc[m][3]);
  }
  __syncthreads();
  float out2[2];
#pragma unroll
  for (int j = 0; j < 2; ++j) {
    int o = t + j * 256;
    float v = 0.f;
#pragma unroll
    for (int sl = 0; sl < 16; ++sl) v += red[sl * 512 + o];
    out2[j] = v;
  }
  int S = gridDim.y;
  if (S > 1) {
    int M = gridDim.z * 8;
#pragma unroll
    for (int j = 0; j < 2; ++j) {
      int o = t + j * 256; int m = o >> 6, cc = o & 63;
      C[((size_t)s * M + row0 + m) * N + c0 + cc] = out2[j];
    }
  } else {
#pragma unroll
    for (int j = 0; j < 2; ++j) {
      int o = t + j * 256; int m = o >> 6, cc = o & 63;
      int col2 = c0 + cc;
      float v = out2[j] + bias[col2];
      if (resid) v += resid[(size_t)(row0 + m) * N + col2];
      if (relu) v = fmaxf(v, 0.0f);
      C[(size_t)(row0 + m) * N + col2] = v;
    }
  }
}

__global__ __launch_bounds__(256) void reduce_br_kernel(const float* __restrict__ part, int S, int M,
                                 const float* __restrict__ bias,
                                 const float* __restrict__ resid,
                                 float* __restrict__ outp) {
  int r = blockIdx.x, t = threadIdx.x;
#pragma unroll
  for (int j = 0; j < 2; ++j) {
    int c = t + j * 256;
    float v = bias[c] + resid[(size_t)r * E + c];
    for (int s = 0; s < S; ++s) v += part[((size_t)s * M + r) * E + c];
    outp[(size_t)r * E + c] = v;
  }
}

__global__ void enc_attn_kernel(const float* __restrict__ qkv, float* __restrict__ o) {
  int b = blockIdx.x >> 3, h = blockIdx.x & 7;
  __shared__ float qs[SS * DH], ks[SS * DH], vs[SS * DH];
  __shared__ float sc[SS][SS];
  int t = threadIdx.x;
  for (int idx = t; idx < SS * DH; idx += 256) {
    int srow = idx / DH, d = idx - srow * DH;
    size_t base = ((size_t)(srow * BB + b)) * (3 * E) + h * DH + d;
    qs[idx] = qkv[base];
    ks[idx] = qkv[base + E];
    vs[idx] = qkv[base + 2 * E];
  }
  __syncthreads();
  for (int p = t; p < SS * SS; p += 256) {
    int qi = p / SS, kj = p - qi * SS;
    float a = 0.f;
    for (int d = 0; d < DH; ++d) a += qs[qi * DH + d] * ks[kj * DH + d];
    sc[qi][kj] = a * 0.125f;
  }
  __syncthreads();
  if (t < SS) {
    float mx = -1e30f;
    for (int j = 0; j < SS; ++j) mx = fmaxf(mx, sc[t][j]);
    float sm = 0.f;
    for (int j = 0; j < SS; ++j) { float ev = expf(sc[t][j] - mx); sc[t][j] = ev; sm += ev; }
    float inv = 1.0f / sm;
    for (int j = 0; j < SS; ++j) sc[t][j] *= inv;
  }
  __syncthreads();
  for (int p = t; p < SS * DH; p += 256) {
    int qi = p / DH, d = p - qi * DH;
    float a = 0.f;
    for (int j = 0; j < SS; ++j) a += sc[qi][j] * vs[j * DH + d];
    o[((size_t)(qi * BB + b)) * E + h * DH + d] = a;
  }
}

// ===========================================================================
// Persistent decode megakernel: 24 steps x 3 layers, ONE dispatch.
// Grid = 256 blocks x 256 threads (LDS ~55KB -> >=1 block/CU on 256 CUs =>
// all blocks co-resident; no other kernel runs concurrently on the stream).
// Phase ordering via device-scope dataflow barrier:
//   producers of phase k: wait(phase_done >= k) -> work -> fence -> arrive;
//   last arriver bumps phase_done. Total order => all RAW/WAR/WAW safe.
// ===========================================================================

struct DecP {
  const float* emb;
  const float* saw; const float* sab; const float* saow; const float* saob;
  const float* caw; const float* cab; const float* caow; const float* caob;
  const float* l1g; const float* l1b; const float* l2g; const float* l2b;
  const float* l3g; const float* l3b;
  const float* f1w; const float* f1b; const float* f2w; const float* f2b;
  const float* ng; const float* nb; const float* vw; const float* vb;
  const float* mem_k; const float* mem_v;
  float* dqkv; float* y_in; float* y1; float* y1raw; float* qca;
  float* y2; float* y2raw; float* dmid; float* partD;
  float* cacheK; float* cacheV; float* out;
  unsigned long long* vmax; int* tokens; int* pd; int* arr;
};

__device__ inline void mwait(int* pd, int target) {
  __syncthreads();
  if (threadIdx.x == 0) {
    int spins = 0;
    while (__hip_atomic_load(pd, __ATOMIC_RELAXED, __HIP_MEMORY_SCOPE_AGENT) < target) {
      if (spins < 32) __builtin_amdgcn_s_sleep(1);
      else            __builtin_amdgcn_s_sleep(32);
      ++spins;
    }
    __threadfence();   // acquire: invalidate local L1/L2 before block reads
  }
  __syncthreads();
}

__device__ inline void msignal(int* arr, int* pd, int phidx, int nprod) {
  __syncthreads();     // all block threads' stores issued (vmcnt drained)
  if (threadIdx.x == 0) {
    __threadfence();   // release: flush this XCD's L2
    int a = __hip_atomic_fetch_add(&arr[phidx], 1, __ATOMIC_ACQ_REL, __HIP_MEMORY_SCOPE_AGENT);
    if (a + 1 == nprod)
      __hip_atomic_fetch_add(pd, 1, __ATOMIC_ACQ_REL, __HIP_MEMORY_SCOPE_AGENT);
  }
}

// In-place row LayerNorm of 8x512 tile in LDS.
__device__ inline void ln_lds(float* Al, const float* __restrict__ g,
                              const float* __restrict__ b, float* rm, float* rrs) {
  int t = threadIdx.x;
  int rr = t >> 5, q = t & 31;
  const float* ar = Al + rr * 512;
  float sm = 0.f, s2 = 0.f;
  for (int j = q; j < 512; j += 32) { float v = ar[j]; sm += v; s2 += v * v; }
  for (int off = 16; off; off >>= 1) {
    sm += __shfl_down(sm, off, 32);
    s2 += __shfl_down(s2, off, 32);
  }
  if (q == 0) {
    float m = sm * (1.0f / 512.0f);
    float var = s2 * (1.0f / 512.0f) - m * m;
    rm[rr] = m;
    rrs[rr] = 1.0f / sqrtf(var + 1e-5f);
  }
  __syncthreads();
  for (int idx = t; idx < 4096; idx += 256) {
    int r2 = idx >> 9, c2 = idx & 511;
    Al[idx] = (Al[idx] - rm[r2]) * rrs[r2] * g[c2] + b[c2];
  }
  __syncthreads();
}

// One 64-col GEMM slice: out2 <- (Al[8x512]) @ W[512 x ldw][col0..col0+63]
__device__ inline void gemm_slice(const float* __restrict__ W, size_t ldw, int col0,
                                  const float* Al, float* red, float out2[2]) {
  int t = threadIdx.x;
  __syncthreads();               // Al finalized; red free
  int tc = t & 15, tk = t >> 4;
  float acc[8][4];
#pragma unroll
  for (int m = 0; m < 8; ++m) { acc[m][0] = acc[m][1] = acc[m][2] = acc[m][3] = 0.f; }
  const float4* wp = (const float4*)(W + col0 + (tc << 2));
  const size_t ld4 = ldw >> 2;
#pragma unroll 8
  for (int i = 0; i < 32; ++i) {
    int k = tk + (i << 4);
    float4 wv = wp[(size_t)k * ld4];
#pragma unroll
    for (int m = 0; m < 8; ++m) {
      float a = Al[m * 512 + k];
      acc[m][0] += a * wv.x; acc[m][1] += a * wv.y;
      acc[m][2] += a * wv.z; acc[m][3] += a * wv.w;
    }
  }
#pragma unroll
  for (int m = 0; m < 8; ++m) {
    float4* rr = (float4*)&red[tk * 512 + m * 64 + (tc << 2)];
    *rr = make_float4(acc[m][0], acc[m][1], acc[m][2], acc[m][3]);
  }
  __syncthreads();
#pragma unroll
  for (int j = 0; j < 2; ++j) {
    int o = t + j * 256;
    float v = 0.f;
#pragma unroll
    for (int sl = 0; sl < 16; ++sl) v += red[sl * 512 + o];
    out2[j] = v;
  }
}

__global__ __launch_bounds__(256) void decode_mega(DecP P) {
  __shared__ float Al[8 * 512];                 // 16 KB (A tile / attn out)
  __shared__ float red[16 * 512];               // 32 KB (k-split partials / keys)
  __shared__ float sc[64][25];                  // 6.25 KB attn scores
  __shared__ float rm[8], rrs[8];
  __shared__ unsigned long long rowmax[8];
  const int bid = blockIdx.x, t = threadIdx.x;
  int* pd = P.pd; int* arr = P.arr;
  int ph = 0;

  // ---- phase 0: init tokens (block 0) ----
  if (bid == 0) {
    mwait(pd, ph);
    if (t < BB) P.tokens[t] = START_ID;
    msignal(arr, pd, ph, 1);
  }
  ++ph;

  for (int i = 0; i < ML; ++i) {
    for (int l = 0; l < NL; ++l) {
      const float* saw_l  = P.saw  + (size_t)l * E * 3 * E;
      const float* sab_l  = P.sab  + (size_t)l * 3 * E;
      const float* saow_l = P.saow + (size_t)l * E * E;
      const float* saob_l = P.saob + (size_t)l * E;
      const float* caw_l  = P.caw  + (size_t)l * E * 3 * E;
      const float* cab_l  = P.cab  + (size_t)l * 3 * E;
      const float* caow_l = P.caow + (size_t)l * E * E;
      const float* caob_l = P.caob + (size_t)l * E;
      const float* f1w_l  = P.f1w  + (size_t)l * E * FF;
      const float* f1b_l  = P.f1b  + (size_t)l * FF;
      const float* f2w_l  = P.f2w  + (size_t)l * FF * E;
      float* Kc = P.cacheK + (size_t)l * LBUF * BB * E;
      float* Vc = P.cacheV + (size_t)l * LBUF * BB * E;
      const float* Km = P.mem_k + (size_t)l * 192 * E;
      const float* Vm = P.mem_v + (size_t)l * 192 * E;

      // ---- P1: QKV projection (24 blocks); A-prologue = embed gather (l==0)
      //      or prev-layer FFN2 reduce + LN3 (l>0). block0 stores y_in. ----
      if (bid < 24) {
        mwait(pd, ph);
        if (l == 0) {
          for (int idx = t; idx < 1024; idx += 256) {
            int r = idx >> 7, cc = idx & 127;
            int tok = P.tokens[(size_t)i * BB + r];
            ((float4*)Al)[idx] = *(const float4*)(P.emb + (size_t)tok * E + (cc << 2));
          }
          __syncthreads();
        } else {
          const float* f2b_p = P.f2b + (size_t)(l - 1) * E;
          for (int idx = t; idx < 1024; idx += 256) {
            int r = idx >> 7, cc = idx & 127; int c = cc << 2;
            float4 v = *(const float4*)(f2b_p + c);
            float4 rv = *(const float4*)(P.y2 + (size_t)r * E + c);
            v.x += rv.x; v.y += rv.y; v.z += rv.z; v.w += rv.w;
            for (int sl = 0; sl < 4; ++sl) {
              float4 pv = *(const float4*)(P.partD + ((size_t)sl * 8 + r) * E + c);
              v.x += pv.x; v.y += pv.y; v.z += pv.z; v.w += pv.w;
            }
            ((float4*)Al)[idx] = v;
          }
          __syncthreads();
          ln_lds(Al, P.l3g + (size_t)(l - 1) * E, P.l3b + (size_t)(l - 1) * E, rm, rrs);
        }
        if (bid == 0) for (int idx = t; idx < 4096; idx += 256) P.y_in[idx] = Al[idx];
        float out2[2];
        gemm_slice(saw_l, 3 * E, bid * 64, Al, red, out2);
#pragma unroll
        for (int j = 0; j < 2; ++j) {
          int o = t + j * 256; int m = o >> 6, cc = o & 63;
          int col2 = bid * 64 + cc;
          P.dqkv[(size_t)m * (3 * E) + col2] = out2[j] + sab_l[col2];
        }
        msignal(arr, pd, ph, 24);
      }
      ++ph;

      // ---- P2: self-attn (redundant per block) + out-proj + resid (8 blocks) ----
      if (bid < 8) {
        mwait(pd, ph);
        int L = i + 1;
        if (bid == 0) {
          for (int idx = t; idx < 4096; idx += 256) {
            int b = idx >> 9, e = idx & 511;
            const float* row = P.dqkv + (size_t)b * 1536;
            Kc[((size_t)i * BB + b) * E + e] = row[512 + e];
            Vc[((size_t)i * BB + b) * E + e] = row[1024 + e];
          }
        }
        {
          int pr = t >> 2, q = t & 3;
          int b = pr >> 3, h = pr & 7;
          const float4* q4 = (const float4*)(P.dqkv + (size_t)b * 1536 + h * 64);
          for (int j = q; j < L; j += 4) {
            const float* kr = (j == i) ? (P.dqkv + (size_t)b * 1536 + 512 + h * 64)
                                       : (Kc + ((size_t)j * BB + b) * E + h * 64);
            const float4* k4 = (const float4*)kr;
            float a = 0.f;
#pragma unroll
            for (int d = 0; d < 16; ++d) {
              float4 qv = q4[d], kv = k4[d];
              a += qv.x * kv.x + qv.y * kv.y + qv.z * kv.z + qv.w * kv.w;
            }
            sc[pr][j] = a * 0.125f;
          }
        }
        __syncthreads();
        if ((t & 3) == 0) {
          int pr = t >> 2;
          float mx = -1e30f;
          for (int j = 0; j < L; ++j) mx = fmaxf(mx, sc[pr][j]);
          float sm = 0.f;
          for (int j = 0; j < L; ++j) { float ev = expf(sc[pr][j] - mx); sc[pr][j] = ev; sm += ev; }
          float inv = 1.0f / sm;
          for (int j = 0; j < L; ++j) sc[pr][j] *= inv;
        }
        __syncthreads();
        for (int ii = 0; ii < 16; ++ii) {
          int idx = t + (ii << 8);
          int b = idx >> 9, e = idx & 511, h = e >> 6;
          int pr = b * 8 + h;
          float a = 0.f;
          for (int j = 0; j < L; ++j) {
            float vv = (j == i) ? P.dqkv[(size_t)b * 1536 + 1024 + e]
                                : Vc[((size_t)j * BB + b) * E + e];
            a += sc[pr][j] * vv;
          }
          Al[idx] = a;
        }
        float out2[2];
        gemm_slice(saow_l, E, bid * 64, Al, red, out2);
#pragma unroll
        for (int j = 0; j < 2; ++j) {
          int o = t + j * 256; int m = o >> 6, cc = o & 63;
          int col2 = bid * 64 + cc;
          P.y1raw[(size_t)m * E + col2] = out2[j] + saob_l[col2] + P.y_in[(size_t)m * E + col2];
        }
        msignal(arr, pd, ph, 8);
      }
      ++ph;

      // ---- P3: LN1 + cross-attn q projection (8 blocks); block0 stores y1 ----
      if (bid < 8) {
        mwait(pd, ph);
        for (int idx = t; idx < 1024; idx += 256) {
          int r = idx >> 7, cc = idx & 127;
          ((float4*)Al)[idx] = *(const float4*)(P.y1raw + (size_t)r * E + (cc << 2));
        }
        __syncthreads();
        ln_lds(Al, P.l1g + (size_t)l * E, P.l1b + (size_t)l * E, rm, rrs);
        if (bid == 0) for (int idx = t; idx < 4096; idx += 256) P.y1[idx] = Al[idx];
        float out2[2];
        gemm_slice(caw_l, 3 * E, bid * 64, Al, red, out2);
#pragma unroll
        for (int j = 0; j < 2; ++j) {
          int o = t + j * 256; int m = o >> 6, cc = o & 63;
          int col2 = bid * 64 + cc;
          P.qca[(size_t)m * E + col2] = out2[j] + cab_l[col2];
        }
        msignal(arr, pd, ph, 8);
      }
      ++ph;

      // ---- P4: cross-attn (redundant) + out-proj + resid (8 blocks) ----
      if (bid < 8) {
        mwait(pd, ph);
        {
          int pr = t >> 2, q = t & 3;
          int b = pr >> 3, h = pr & 7;
          const float4* q4 = (const float4*)(P.qca + (size_t)b * E + h * 64);
          for (int j = q; j < SS; j += 4) {
            const float4* k4 = (const float4*)(Km + ((size_t)j * BB + b) * E + h * 64);
            float a = 0.f;
#pragma unroll
            for (int d = 0; d < 16; ++d) {
              float4 qv = q4[d], kv = k4[d];
              a += qv.x * kv.x + qv.y * kv.y + qv.z * kv.z + qv.w * kv.w;
            }
            sc[pr][j] = a * 0.125f;
          }
        }
        __syncthreads();
        if ((t & 3) == 0) {
          int pr = t >> 2;
          float mx = -1e30f;
          for (int j = 0; j < SS; ++j) mx = fmaxf(mx, sc[pr][j]);
          float sm = 0.f;
          for (int j = 0; j < SS; ++j) { float ev = expf(sc[pr][j] - mx); sc[pr][j] = ev; sm += ev; }
          float inv = 1.0f / sm;
          for (int j = 0; j < SS; ++j) sc[pr][j] *= inv;
        }
        __syncthreads();
        for (int ii = 0; ii < 16; ++ii) {
          int idx = t + (ii << 8);
          int b = idx >> 9, e = idx & 511, h = e >> 6;
          int pr = b * 8 + h;
          float a = 0.f;
          for (int j = 0; j < SS; ++j) a += sc[pr][j] * Vm[((size_t)j * BB + b) * E + e];
          Al[idx] = a;
        }
        float out2[2];
        gemm_slice(caow_l, E, bid * 64, Al, red, out2);
#pragma unroll
        for (int j = 0; j < 2; ++j) {
          int o = t + j * 256; int m = o >> 6, cc = o & 63;
          int col2 = bid * 64 + cc;
          P.y2raw[(size_t)m * E + col2] = out2[j] + caob_l[col2] + P.y1[(size_t)m * E + col2];
        }
        msignal(arr, pd, ph, 8);
      }
      ++ph;

      // ---- P5: LN2 + FFN1 + relu (32 blocks); block0 stores y2 ----
      if (bid < 32) {
        mwait(pd, ph);
        for (int idx = t; idx < 1024; idx += 256) {
          int r = idx >> 7, cc = idx & 127;
          ((float4*)Al)[idx] = *(const float4*)(P.y2raw + (size_t)r * E + (cc << 2));
        }
        __syncthreads();
        ln_lds(Al, P.l2g + (size_t)l * E, P.l2b + (size_t)l * E, rm, rrs);
        if (bid == 0) for (int idx = t; idx < 4096; idx += 256) P.y2[idx] = Al[idx];
        float out2[2];
        gemm_slice(f1w_l, FF, bid * 64, Al, red, out2);
#pragma unroll
        for (int j = 0; j < 2; ++j) {
          int o = t + j * 256; int m = o >> 6, cc = o & 63;
          int col2 = bid * 64 + cc;
          P.dmid[(size_t)m * FF + col2] = fmaxf(out2[j] + f1b_l[col2], 0.0f);
        }
        msignal(arr, pd, ph, 32);
      }
      ++ph;

      // ---- P6: FFN2 k-split partials (32 blocks: 8 col-tiles x 4 k-slices) ----
      if (bid < 32) {
        mwait(pd, ph);
        int ct = bid & 7, ks = bid >> 3;
        int kbase = ks * 512;
        for (int idx = t; idx < 1024; idx += 256) {
          int r = idx >> 7, cc = idx & 127;
          ((float4*)Al)[idx] = *(const float4*)(P.dmid + (size_t)r * FF + kbase + (cc << 2));
        }
        float out2[2];
        gemm_slice(f2w_l + (size_t)kbase * E, E, ct * 64, Al, red, out2);
#pragma unroll
        for (int j = 0; j < 2; ++j) {
          int o = t + j * 256; int m = o >> 6, cc = o & 63;
          P.partD[((size_t)ks * 8 + m) * E + ct * 64 + cc] = out2[j];
        }
        msignal(arr, pd, ph, 32);
      }
      ++ph;
    }

    // ---- P7: vocab GEMM (256 blocks, <=2 tiles each); prologue =
    //      last-layer FFN2 reduce + LN3 + final LN; per-block argmax keys ----
    {
      mwait(pd, ph);
      const float* f2b_p = P.f2b + (size_t)(NL - 1) * E;
      for (int idx = t; idx < 1024; idx += 256) {
        int r = idx >> 7, cc = idx & 127; int c = cc << 2;
        float4 v = *(const float4*)(f2b_p + c);
        float4 rv = *(const float4*)(P.y2 + (size_t)r * E + c);
        v.x += rv.x; v.y += rv.y; v.z += rv.z; v.w += rv.w;
        for (int sl = 0; sl < 4; ++sl) {
          float4 pv = *(const float4*)(P.partD + ((size_t)sl * 8 + r) * E + c);
          v.x += pv.x; v.y += pv.y; v.z += pv.z; v.w += pv.w;
        }
        ((float4*)Al)[idx] = v;
      }
      __syncthreads();
      ln_lds(Al, P.l3g + (size_t)(NL - 1) * E, P.l3b + (size_t)(NL - 1) * E, rm, rrs);
      ln_lds(Al, P.ng, P.nb, rm, rrs);
      if (t < 8) rowmax[t] = 0ull;
      __syncthreads();
      float* dist = P.out + 192 + (size_t)i * (8 * VTOK);
      for (int tt = 0; tt < 2; ++tt) {
        int tile = bid + tt * 256;
        if (tile >= 500) break;
        int col0 = tile * 64;
        float out2[2];
        gemm_slice(P.vw, VTOK, col0, Al, red, out2);
#pragma unroll
        for (int j = 0; j < 2; ++j) {
          int o = t + j * 256; int m = o >> 6, cc = o & 63;
          int col2 = col0 + cc;
          float v = out2[j] + P.vb[col2];
          dist[(size_t)m * VTOK + col2] = v;
          out2[j] = v;
        }
        __syncthreads();
        unsigned long long* keys = (unsigned long long*)red;
#pragma unroll
        for (int j = 0; j < 2; ++j) {
          int o = t + j * 256;
          unsigned int fb = __float_as_uint(out2[j]);
          fb = (fb & 0x80000000u) ? ~fb : (fb | 0x80000000u);
          int col2 = col0 + (o & 63);
          keys[o] = ((unsigned long long)fb << 32) |
                    (unsigned long long)(0xFFFFFFFFu - (unsigned)col2);
        }
        __syncthreads();
        if (t < 64) {
          for (int m = 0; m < 8; ++m) {
            unsigned long long k = keys[m * 64 + t];
            for (int off = 32; off; off >>= 1) {
              unsigned long long o2 = __shfl_down(k, off);
              if (o2 > k) k = o2;
            }
            if (t == 0 && k > rowmax[m]) rowmax[m] = k;
          }
        }
        __syncthreads();
      }
      if (t < 8) P.vmax[(size_t)bid * 8 + t] = rowmax[t];
      msignal(arr, pd, ph, 256);
    }
    ++ph;

    // ---- P8: argmax reduce + emit tokens (block 0) ----
    if (bid == 0) {
      mwait(pd, ph);
      unsigned long long* redu = (unsigned long long*)red;
      for (int r = 0; r < 8; ++r) {
        redu[t] = P.vmax[(size_t)t * 8 + r];
        __syncthreads();
        for (int s = 128; s > 0; s >>= 1) {
          if (t < s) { if (redu[t + s] > redu[t]) redu[t] = redu[t + s]; }
          __syncthreads();
        }
        if (t == 0) {
          unsigned int idx = 0xFFFFFFFFu - (unsigned int)(redu[0] & 0xFFFFFFFFull);
          P.tokens[(size_t)(i + 1) * BB + r] = (int)idx;
          P.out[(size_t)i * BB + r] = (float)idx;
        }
        __syncthreads();
      }
      msignal(arr, pd, ph, 1);
    }
    ++ph;
  }
}

// ===========================================================================
extern "C" void kernel_launch(void* const* d_in, const int* in_sizes, int n_in,
                              void* d_out, int out_size, void* d_ws, size_t ws_size,
                              hipStream_t stream) {
  (void)in_sizes; (void)n_in; (void)out_size; (void)ws_size;
  const int*   inp   = (const int*)d_in[0];
  const float* emb   = (const float*)d_in[1];
  const float* e_aw  = (const float*)d_in[2];
  const float* e_ab  = (const float*)d_in[3];
  const float* e_aow = (const float*)d_in[4];
  const float* e_aob = (const float*)d_in[5];
  const float* e_l1g = (const float*)d_in[6];
  const float* e_l1b = (const float*)d_in[7];
  const float* e_l2g = (const float*)d_in[8];
  const float* e_l2b = (const float*)d_in[9];
  const float* e_f1w = (const float*)d_in[10];
  const float* e_f1b = (const float*)d_in[11];
  const float* e_f2w = (const float*)d_in[12];
  const float* e_f2b = (const float*)d_in[13];
  const float* e_ng  = (const float*)d_in[14];
  const float* e_nb  = (const float*)d_in[15];
  const float* d_saw = (const float*)d_in[16];
  const float* d_sab = (const float*)d_in[17];
  const float* d_saow= (const float*)d_in[18];
  const float* d_saob= (const float*)d_in[19];
  const float* d_caw = (const float*)d_in[20];
  const float* d_cab = (const float*)d_in[21];
  const float* d_caow= (const float*)d_in[22];
  const float* d_caob= (const float*)d_in[23];
  const float* d_l1g = (const float*)d_in[24];
  const float* d_l1b = (const float*)d_in[25];
  const float* d_l2g = (const float*)d_in[26];
  const float* d_l2b = (const float*)d_in[27];
  const float* d_l3g = (const float*)d_in[28];
  const float* d_l3b = (const float*)d_in[29];
  const float* d_f1w = (const float*)d_in[30];
  const float* d_f1b = (const float*)d_in[31];
  const float* d_f2w = (const float*)d_in[32];
  const float* d_f2b = (const float*)d_in[33];
  const float* d_ng  = (const float*)d_in[34];
  const float* d_nb  = (const float*)d_in[35];
  const float* voc_w = (const float*)d_in[36];
  const float* voc_b = (const float*)d_in[37];
  float* out = (float*)d_out;

  // workspace carve-up (floats)
  float* p = (float*)d_ws;
  auto alloc = [&](size_t n) { float* r = p; p += n; return r; };
  float* enc_x   = alloc(192 * 512);
  float* enc_tmp = alloc(192 * 2048);
  float* enc_ao  = alloc(192 * 512);
  float* enc_raw = alloc(192 * 512);
  float* memry   = alloc(192 * 512);
  float* mem_k   = alloc(3 * 192 * 512);
  float* mem_v   = alloc(3 * 192 * 512);
  float* partE   = alloc(4 * 192 * 512);
  float* dqkv    = alloc(8 * 1536);
  float* y_in    = alloc(8 * 512);
  float* y1      = alloc(8 * 512);
  float* y1raw   = alloc(8 * 512);
  float* qca     = alloc(8 * 512);
  float* y2      = alloc(8 * 512);
  float* y2raw   = alloc(8 * 512);
  float* dmid    = alloc(8 * 2048);
  float* partD   = alloc(4 * 8 * 512);
  float* cacheK  = alloc(3 * LBUF * 8 * 512);
  float* cacheV  = alloc(3 * LBUF * 8 * 512);
  int* tokens    = (int*)alloc(256);                       // LBUF*8 = 200 ints
  unsigned long long* vmax = (unsigned long long*)alloc(4096); // 256*8 u64 = 16KB
  int* syncmem   = (int*)alloc(2048);                      // pd + arr (8KB)

  int* pd  = syncmem;        // own cache line
  int* arr = syncmem + 64;   // 481 phase arrival counters

  // ---------------- encoder (host-sequenced) ----------------
  enc_embed_kernel<<<dim3(192), dim3(256), 0, stream>>>(inp, emb, enc_x);
  for (int l = 0; l < NL; ++l) {
    const float* w  = e_aw  + (size_t)l * E * 3 * E;
    const float* bq = e_ab  + (size_t)l * 3 * E;
    fgemm_kernel<<<dim3(24, 1, 24), dim3(256), 0, stream>>>(
        enc_x, E, w, 3 * E, 3 * E, bq, nullptr, enc_tmp, 0);
    enc_attn_kernel<<<dim3(64), dim3(256), 0, stream>>>(enc_tmp, enc_ao);
    fgemm_kernel<<<dim3(8, 1, 24), dim3(256), 0, stream>>>(
        enc_ao, E, e_aow + (size_t)l * E * E, E, E, e_aob + (size_t)l * E,
        enc_x, enc_raw, 0);
    ln_kernel<<<dim3(192), dim3(256), 0, stream>>>(enc_raw, e_l1g + l * E, e_l1b + l * E, enc_x);
    fgemm_kernel<<<dim3(32, 1, 24), dim3(256), 0, stream>>>(
        enc_x, E, e_f1w + (size_t)l * E * FF, FF, FF, e_f1b + (size_t)l * FF,
        nullptr, enc_tmp, 1);
    fgemm_kernel<<<dim3(8, 4, 24), dim3(256), 0, stream>>>(
        enc_tmp, FF, e_f2w + (size_t)l * FF * E, E, E, nullptr,
        nullptr, partE, 0);
    reduce_br_kernel<<<dim3(192), dim3(256), 0, stream>>>(
        partE, 4, 192, e_f2b + (size_t)l * E, enc_x, enc_raw);
    ln_kernel<<<dim3(192), dim3(256), 0, stream>>>(enc_raw, e_l2g + l * E, e_l2b + l * E, enc_x);
  }
  ln_kernel<<<dim3(192), dim3(256), 0, stream>>>(enc_x, e_ng, e_nb, memry);

  for (int l = 0; l < NL; ++l) {
    const float* w  = d_caw + (size_t)l * E * 3 * E;
    const float* bq = d_cab + (size_t)l * 3 * E;
    fgemm_kernel<<<dim3(8, 1, 24), dim3(256), 0, stream>>>(
        memry, E, w + E, 3 * E, E, bq + E, nullptr, mem_k + (size_t)l * 192 * 512, 0);
    fgemm_kernel<<<dim3(8, 1, 24), dim3(256), 0, stream>>>(
        memry, E, w + 2 * E, 3 * E, E, bq + 2 * E, nullptr, mem_v + (size_t)l * 192 * 512, 0);
  }

  // ---------------- decode: ONE persistent kernel ----------------
  hipMemsetAsync(syncmem, 0, 2048 * sizeof(int), stream);

  DecP P;
  P.emb = emb;
  P.saw = d_saw; P.sab = d_sab; P.saow = d_saow; P.saob = d_saob;
  P.caw = d_caw; P.cab = d_cab; P.caow = d_caow; P.caob = d_caob;
  P.l1g = d_l1g; P.l1b = d_l1b; P.l2g = d_l2g; P.l2b = d_l2b;
  P.l3g = d_l3g; P.l3b = d_l3b;
  P.f1w = d_f1w; P.f1b = d_f1b; P.f2w = d_f2w; P.f2b = d_f2b;
  P.ng = d_ng; P.nb = d_nb; P.vw = voc_w; P.vb = voc_b;
  P.mem_k = mem_k; P.mem_v = mem_v;
  P.dqkv = dqkv; P.y_in = y_in; P.y1 = y1; P.y1raw = y1raw; P.qca = qca;
  P.y2 = y2; P.y2raw = y2raw; P.dmid = dmid; P.partD = partD;
  P.cacheK = cacheK; P.cacheV = cacheV; P.out = out;
  P.vmax = vmax; P.tokens = tokens; P.pd = pd; P.arr = arr;

  decode_mega<<<dim3(256), dim3(256), 0, stream>>>(P);
}